// Round 5
// baseline (701.370 us; speedup 1.0000x reference)
//
#include <hip/hip_runtime.h>

#define N_NODES 50000
#define N_EDGES 600000
#define DIM     128
#define VOCAB   512
#define LN_EPS  1e-5f
#define FIX20   1048576.0f    // 2^20 fixed-point scale for weight sums (26-bit field)
#define WSC     65535.0f      // 16-bit fixed-point scale for edge weights
#define BCAP    64            // fixed CSR bucket capacity (max in-degree << 64)
#define NBLK    512           // 2 blocks/CU x 256 CUs -> all co-resident

typedef unsigned int uint;
typedef unsigned long long ull;
typedef unsigned short ushort;
typedef __attribute__((ext_vector_type(8))) short s8v;   // 8 bf16 (4 VGPRs)
typedef __attribute__((ext_vector_type(4))) float f4v;   // 4 fp32 acc
typedef __attribute__((ext_vector_type(4))) int   i4v;
typedef __attribute__((ext_vector_type(4))) float fv4;
typedef __attribute__((ext_vector_type(2))) float f2v;

// round-to-nearest-even fp32 -> bf16 (as uint16 in low bits)
__device__ __forceinline__ uint f2bf(float f) {
    uint u = __float_as_uint(f);
    return (u + 0x7fffu + ((u >> 16) & 1u)) >> 16;
}
__device__ __forceinline__ float bf_lo(uint p) { return __uint_as_float(p << 16); }
__device__ __forceinline__ float bf_hi(uint p) { return __uint_as_float(p & 0xffff0000u); }
// pack word: {count:6 | fixsum:26}, fixsum scaled by 2^20
__device__ __forceinline__ float dis_of(uint pv) {
    return rsqrtf(1.0f + (float)(pv & 0x03ffffffu) * (1.0f / FIX20));
}

// Manual grid barrier (persistent-kernel pattern; all NBLK blocks co-resident
// by __launch_bounds__(256,2) + grid=2*CUs). Monotonic counter, one per run,
// zeroed by a captured hipMemsetAsync. Release-add + acquire-poll at agent
// scope handles cross-XCD L2 visibility (same scheme as hip CG grid.sync).
__device__ __forceinline__ void grid_bar(uint* cnt, uint target) {
    __syncthreads();
    __threadfence();                                  // release block's writes
    if (threadIdx.x == 0) {
        __hip_atomic_fetch_add(cnt, 1u, __ATOMIC_RELEASE, __HIP_MEMORY_SCOPE_AGENT);
        while (__hip_atomic_load(cnt, __ATOMIC_ACQUIRE, __HIP_MEMORY_SCOPE_AGENT)
               < target)
            __builtin_amdgcn_s_sleep(2);
    }
    __syncthreads();
}

struct GcnParams {
    const int*   ei;     // [2,E]
    const float* ew;
    uint2*       pairN;  // {pack: count|fixsum, nid}
    const int*   nid;
    uint*        epack;  // buckets: {src:16|w16}
    const float* emb;
    const float* W1;
    uint*        hembB;  // emb@W1 bf16x2
    const float* W2;
    ushort*      Wp;     // W2 MFMA B-frags
    uint*        x1b;    // layer-1 out bf16x2
    char*        h8;     // layer-2 matmul int8
    float*       rsc;    // per-row scale (carries dis)
    const float* b1; const float* g1; const float* be1;
    const float* b2; const float* g2; const float* be2;
    float*       out;
    uint*        bar;    // grid barrier counter
};

// ---------------------------------------------------------------------------
// Phase-1 sub-path: per-edge 32-bit atomic {count:6, fixsum:26} -> rank,
// then direct 4B-record scatter epack[dst*BCAP + rank] = {src:16 | w16}.
__device__ __forceinline__ void deg_step(int vb, int tid, const GcnParams& P) {
    int e0 = (vb * 256 + tid) * 4;
    if (e0 >= N_EDGES) return;
    i4v s4 = __builtin_nontemporal_load((const i4v*)(P.ei + e0));
    i4v c4 = __builtin_nontemporal_load((const i4v*)(P.ei + N_EDGES + e0));
    fv4 w4 = __builtin_nontemporal_load((const fv4*)(P.ew + e0));
    int   s[4] = {s4.x, s4.y, s4.z, s4.w};
    int   c[4] = {c4.x, c4.y, c4.z, c4.w};
    float w[4] = {w4.x, w4.y, w4.z, w4.w};
    uint r[4];
    #pragma unroll
    for (int k = 0; k < 4; k++) {
        uint a = (1u << 26) | (uint)__float2int_rn(w[k] * FIX20);
        r[k] = atomicAdd(&((uint*)P.pairN)[2 * (size_t)c[k]], a);
    }
    #pragma unroll
    for (int k = 0; k < 4; k++) {
        uint rk = r[k] >> 26;                        // rank among dst's edges
        uint wq = (uint)__float2int_rn(w[k] * WSC);
        P.epack[(size_t)c[k] * BCAP + rk] = (uint)s[k] | (wq << 16);
    }
}

// Phase-1 sub-path: layer-1 matmul Hb = emb @ W1 (fp32 -> bf16x2), 64 rows/vb.
__device__ __forceinline__ void mm1_step(int bx, int tid, float* Wt, float* Xt,
                                         const GcnParams& P) {
    const float* X = P.emb;
    const float* W = P.W1;
    int tx = tid & 31, ty = tid >> 5;
    int r0 = bx * 64;
    float acc[8][4];
    #pragma unroll
    for (int j = 0; j < 8; j++)
        #pragma unroll
        for (int c = 0; c < 4; c++) acc[j][c] = 0.f;

    for (int kb = 0; kb < 128; kb += 32) {
        __syncthreads();
        #pragma unroll
        for (int q = 0; q < 4; q++) {
            int f = q * 256 + tid;
            ((float4*)Wt)[f] = *(const float4*)(W + kb * 128 + f * 4);
        }
        #pragma unroll
        for (int q = 0; q < 2; q++) {
            int f = q * 256 + tid;
            int row = f >> 3, cs = f & 7;
            int gr = r0 + row;
            float4 xv = make_float4(0.f, 0.f, 0.f, 0.f);
            if (gr < VOCAB) xv = *(const float4*)(X + (size_t)gr * 128 + kb + cs * 4);
            *(float4*)(Xt + row * 36 + cs * 4) = xv;
        }
        __syncthreads();
        #pragma unroll
        for (int k = 0; k < 32; k += 4) {
            float wv[4][4];
            #pragma unroll
            for (int kk = 0; kk < 4; kk++) {
                float4 t4 = *(const float4*)(Wt + (k + kk) * 128 + tx * 4);
                wv[kk][0] = t4.x; wv[kk][1] = t4.y; wv[kk][2] = t4.z; wv[kk][3] = t4.w;
            }
            #pragma unroll
            for (int j = 0; j < 8; j++) {
                float4 xv = *(const float4*)(Xt + (ty * 8 + j) * 36 + k);
                float xs[4] = {xv.x, xv.y, xv.z, xv.w};
                #pragma unroll
                for (int kk = 0; kk < 4; kk++)
                    #pragma unroll
                    for (int c = 0; c < 4; c++)
                        acc[j][c] = fmaf(xs[kk], wv[kk][c], acc[j][c]);
            }
        }
    }
    #pragma unroll
    for (int j = 0; j < 8; j++) {
        int gr = r0 + ty * 8 + j;
        if (gr < VOCAB) {
            uint p0 = f2bf(acc[j][0]) | (f2bf(acc[j][1]) << 16);
            uint p1 = f2bf(acc[j][2]) | (f2bf(acc[j][3]) << 16);
            ((uint2*)P.hembB)[(size_t)gr * 32 + tx] = make_uint2(p0, p1);
        }
    }
}

// Phase-1 sub-path: W2 prepack (16384 elems) then pairN[i].y = node_ids[i]
// (nid words disjoint from the atomic pack words -> no ordering hazard).
__device__ __forceinline__ void prep_step(int o, const GcnParams& P) {
    if (o < 16384) {
        int j = o & 7, lane = (o >> 3) & 63, chunk = o >> 9;
        int kc = chunk & 3, nc = chunk >> 2;
        int k = kc * 32 + (lane >> 4) * 8 + j;
        int n = nc * 16 + (lane & 15);
        P.Wp[o] = (ushort)f2bf(P.W2[k * 128 + n]);
    } else {
        int i = o - 16384;
        if (i < N_NODES) ((uint*)P.pairN)[2 * (size_t)i + 1] = (uint)P.nid[i];
    }
}

// ---------------------------------------------------------------------------
// Phase 3: MFMA bf16 matmul (layer 2), per-row int8 output.
// rowscale[r] = max|row r|/127 * dis[r]  (dis folded -> agg2 uses raw w).
__device__ __forceinline__ void mm2_step(int wid, int lane, const GcnParams& P) {
    int r0 = wid * 16;
    if (r0 >= N_NODES) return;
    int quad = lane >> 4, lo = lane & 15;
    const uint* xrow = P.x1b + (size_t)(r0 + lo) * 64 + quad * 4;
    s8v a[4];
    #pragma unroll
    for (int kc = 0; kc < 4; kc++) a[kc] = *(const s8v*)(xrow + kc * 16);
    f4v acc[8];
    #pragma unroll
    for (int nc = 0; nc < 8; nc++) {
        acc[nc] = (f4v){0.f, 0.f, 0.f, 0.f};
        #pragma unroll
        for (int kc = 0; kc < 4; kc++) {
            s8v b = *(const s8v*)(P.Wp + (size_t)((nc * 4 + kc) * 64 + lane) * 8);
            acc[nc] = __builtin_amdgcn_mfma_f32_16x16x32_bf16(a[kc], b, acc[nc], 0, 0, 0);
        }
    }
    float m[4];
    #pragma unroll
    for (int r = 0; r < 4; r++) {
        m[r] = 0.f;
        #pragma unroll
        for (int nc = 0; nc < 8; nc++) m[r] = fmaxf(m[r], fabsf(acc[nc][r]));
    }
    #pragma unroll
    for (int o = 1; o <= 8; o <<= 1)
        #pragma unroll
        for (int r = 0; r < 4; r++) m[r] = fmaxf(m[r], __shfl_xor(m[r], o, 64));
    #pragma unroll
    for (int r = 0; r < 4; r++) {
        float inv = (m[r] > 0.f) ? 127.0f / m[r] : 0.f;
        if (lo == 0) {
            int rr = r0 + quad * 4 + r;
            P.rsc[rr] = m[r] * (1.0f / 127.0f) * dis_of(P.pairN[rr].x);
        }
        char* hp = P.h8 + (size_t)(r0 + quad * 4 + r) * 128 + lo;
        #pragma unroll
        for (int nc = 0; nc < 8; nc++)
            hp[nc * 16] = (char)__float2int_rn(acc[nc][r] * inv);
    }
}

// ---------------------------------------------------------------------------
// Phases 2/4: fused aggregation + self-loop + bias + residual + LN.
// One wave per node; lane owns dims {2*lane, 2*lane+1}.
// Batch-16 MLP: 16 records in 4 uniform uint4 loads, then ALL level-2
// gathers, then ALL row gathers -> ~3 serial round trips per node.
template<bool RESID_BF, bool OUT_BF, bool GI8>
__device__ __forceinline__ void agg_step(int i, int lane,
        const uint2* __restrict__ pairN, const uint* __restrict__ epack,
        const void* __restrict__ hb, const float* __restrict__ rowscale,
        const void* __restrict__ resid, const float* __restrict__ bias,
        const float* __restrict__ gamma, const float* __restrict__ beta,
        void* __restrict__ out) {
    int iw = __builtin_amdgcn_readfirstlane(i);      // wave-uniform
    uint2 pnw = pairN[iw];
    uint pv = pnw.x;
    int deg = (int)(pv >> 26);
    float dl = dis_of(pv);
    int hri = GI8 ? iw : (int)pnw.y;
    float slo, shi;
    if (GI8) {
        uint ps = ((const ushort*)hb)[(size_t)hri * 64 + lane];
        float sc0 = rowscale[hri];                   // folded: dl * raw_scale
        slo = sc0 * (float)(signed char)(ps & 0xffu);
        shi = sc0 * (float)(signed char)(ps >> 8);
    } else {
        uint ps = ((const uint*)hb)[(size_t)hri * 64 + lane];
        slo = bf_lo(ps); shi = bf_hi(ps);
    }
    // self-loop: final *dl gives dl^2*h (GI8: sc already carries one dl)
    float sx[4] = {GI8 ? slo : dl * slo, 0.f, 0.f, 0.f};
    float sy[4] = {GI8 ? shi : dl * shi, 0.f, 0.f, 0.f};
    const uint* ep = epack + (size_t)iw * BCAP;

    for (int j0 = 0; j0 < deg; j0 += 16) {
        uint4 rv0 = ((const uint4*)(ep + j0))[0];
        uint4 rv1 = ((const uint4*)(ep + j0))[1];
        uint4 rv2 = ((const uint4*)(ep + j0))[2];
        uint4 rv3 = ((const uint4*)(ep + j0))[3];
        uint rec[16] = {rv0.x, rv0.y, rv0.z, rv0.w,
                        rv1.x, rv1.y, rv1.z, rv1.w,
                        rv2.x, rv2.y, rv2.z, rv2.w,
                        rv3.x, rv3.y, rv3.z, rv3.w};
        uint src[16];
        #pragma unroll
        for (int k = 0; k < 16; k++)
            src[k] = (j0 + k < deg) ? (rec[k] & 0xffffu) : 0u;   // clamp -> safe row
        uint qv[16];
        float scv[16];
        if (GI8) {
            #pragma unroll
            for (int k = 0; k < 16; k++)
                qv[k] = ((const ushort*)hb)[(size_t)src[k] * 64 + lane];
            #pragma unroll
            for (int k = 0; k < 16; k++)
                scv[k] = rowscale[src[k]];
        } else {
            uint2 pnk[16];
            #pragma unroll
            for (int k = 0; k < 16; k++)
                pnk[k] = pairN[src[k]];              // {pack, nid} one gather
            #pragma unroll
            for (int k = 0; k < 16; k++)
                qv[k] = ((const uint*)hb)[(size_t)pnk[k].y * 64 + lane];
            #pragma unroll
            for (int k = 0; k < 16; k++)
                scv[k] = (float)(pnk[k].x & 0x03ffffffu);
        }
        #pragma unroll
        for (int k = 0; k < 16; k++) {
            float w = (j0 + k < deg) ? (float)(rec[k] >> 16) * (1.0f / WSC) : 0.f;
            float lo, hi;
            if (GI8) {
                w *= scv[k];                         // raw w * (dis_src*scale_src)
                lo = (float)(signed char)(qv[k] & 0xffu);
                hi = (float)(signed char)(qv[k] >> 8);
            } else {
                w *= rsqrtf(1.0f + scv[k] * (1.0f / FIX20));
                lo = bf_lo(qv[k]); hi = bf_hi(qv[k]);
            }
            sx[k & 3] += w * lo;
            sy[k & 3] += w * hi;
        }
    }
    float acc0 = (sx[0] + sx[1]) + (sx[2] + sx[3]);
    float acc1 = (sy[0] + sy[1]) + (sy[2] + sy[3]);
    float2 xr;
    if (RESID_BF) {
        uint pr = __builtin_nontemporal_load((const uint*)resid + (size_t)hri * 64 + lane);
        xr = make_float2(bf_lo(pr), bf_hi(pr));
    } else {
        xr = ((const float2*)resid)[(size_t)hri * 64 + lane];
    }
    float2 bi = ((const float2*)bias)[lane];
    float v0 = xr.x + dl * acc0 + bi.x;
    float v1 = xr.y + dl * acc1 + bi.y;
    float s1 = v0 + v1, s2 = v0 * v0 + v1 * v1;
    #pragma unroll
    for (int o = 32; o > 0; o >>= 1) {
        s1 += __shfl_xor(s1, o, 64);
        s2 += __shfl_xor(s2, o, 64);
    }
    float mu   = s1 * (1.0f / DIM);
    float var  = s2 * (1.0f / DIM) - mu * mu;
    float rstd = rsqrtf(var + LN_EPS);
    float2 ga = ((const float2*)gamma)[lane];
    float2 be = ((const float2*)beta)[lane];
    float o0 = (v0 - mu) * rstd * ga.x + be.x;
    float o1 = (v1 - mu) * rstd * ga.y + be.y;
    if (OUT_BF) {
        __builtin_nontemporal_store(f2bf(o0) | (f2bf(o1) << 16),
                                    (uint*)out + (size_t)i * 64 + lane);
    } else {
        f2v ov = {o0, o1};
        __builtin_nontemporal_store(ov, (f2v*)((float2*)out + (size_t)i * 64 + lane));
    }
}

// ---------------------------------------------------------------------------
// ONE persistent kernel for the whole pipeline, plain launch (no cooperative
// API: it is not graph-capturable -> round-4 silent no-run). 512 blocks x
// 256 threads; __launch_bounds__(256,2) guarantees 2 blocks/CU co-residency
// so the manual grid barrier cannot deadlock.
__global__ __launch_bounds__(256, 2) void fused_gcn(GcnParams P) {
    __shared__ float Wt[32 * 128];
    __shared__ float Xt[64 * 36];
    int tid = threadIdx.x;
    int bid = blockIdx.x;
    const int nb = NBLK;
    int lane = tid & 63, wv = tid >> 6;

    // ---- phase 0: zero pairN (replaces hipMemsetAsync) ----
    for (int t = bid * 256 + tid; t < N_NODES * 2; t += nb * 256)
        ((uint*)P.pairN)[t] = 0u;
    grid_bar(P.bar, 1 * nb);

    // ---- phase 1: deg atomics + scatter | mm1 | W2/nid prep ----
    constexpr int nbDeg = (N_EDGES / 4 + 255) / 256;       // 586
    constexpr int nmm   = (VOCAB + 63) / 64;               // 8
    constexpr int nTail = 64 + (N_NODES + 255) / 256;      // 260
    constexpr int NVB1  = nbDeg + nmm + nTail;             // 854
    for (int vb = bid; vb < NVB1; vb += nb) {
        if (vb < nbDeg)            deg_step(vb, tid, P);
        else if (vb < nbDeg + nmm) mm1_step(vb - nbDeg, tid, Wt, Xt, P);
        else                       prep_step((vb - nbDeg - nmm) * 256 + tid, P);
    }
    grid_bar(P.bar, 2 * nb);

    // ---- phase 2: agg1 (bf16 vocab table; {dis,nid}[src] via pairN) ----
    constexpr int NVBA = (N_NODES + 3) / 4;                // 12500
    for (int vb = bid; vb < NVBA; vb += nb) {
        int i = vb * 4 + wv;
        if (i < N_NODES)
            agg_step<false, true, false>(i, lane, P.pairN, P.epack, P.hembB,
                                         nullptr, P.emb, P.b1, P.g1, P.be1, P.x1b);
    }
    grid_bar(P.bar, 3 * nb);

    // ---- phase 3: mm2 (MFMA -> int8, rowscale folds dis) ----
    constexpr int NVB3 = (N_NODES / 16 + 3) / 4;           // 782
    for (int vb = bid; vb < NVB3; vb += nb)
        mm2_step(vb * 4 + wv, lane, P);
    grid_bar(P.bar, 4 * nb);

    // ---- phase 4: agg2 (int8 table, rowscale-folded weights) -> out ----
    for (int vb = bid; vb < NVBA; vb += nb) {
        int i = vb * 4 + wv;
        if (i < N_NODES)
            agg_step<true, false, true>(i, lane, P.pairN, P.epack, P.h8,
                                        P.rsc, P.x1b, P.b2, P.g2, P.be2, P.out);
    }
}

// ---------------------------------------------------------------------------
extern "C" void kernel_launch(void* const* d_in, const int* in_sizes, int n_in,
                              void* d_out, int out_size, void* d_ws, size_t ws_size,
                              hipStream_t stream) {
    // workspace carve-out (256B aligned)
    char* p = (char*)d_ws;
    auto alloc = [&](size_t bytes) {
        char* r = p;
        p += (bytes + 255) & ~(size_t)255;
        return r;
    };
    char*   h8      = (char*)  alloc((size_t)N_NODES * DIM);       // 6.4 MB int8
    float*  rsc     = (float*) alloc((size_t)N_NODES * 4);         // 200 KB scales
    uint*   x1b     = (uint*)  alloc((size_t)N_NODES * 64 * 4);    // 12.8 MB bf16x2
    uint*   hembB   = (uint*)  alloc((size_t)VOCAB * 64 * 4);      // 128 KB bf16x2
    ushort* Wp      = (ushort*)alloc((size_t)128 * 128 * 2);       // 32 KB B-frags
    uint2*  pairN   = (uint2*) alloc((size_t)N_NODES * 8);         // 400 KB {pack,nid}
    uint*   epack   = (uint*)  alloc((size_t)N_NODES * BCAP * 4);  // 12.8 MB
    uint*   bar     = (uint*)  alloc(256);                         // grid barrier

    GcnParams P;
    P.ei    = (const int*)  d_in[1];
    P.ew    = (const float*)d_in[2];
    P.pairN = pairN;
    P.nid   = (const int*)  d_in[0];
    P.epack = epack;
    P.emb   = (const float*)d_in[3];
    P.W1    = (const float*)d_in[4];
    P.hembB = hembB;
    P.W2    = (const float*)d_in[6];
    P.Wp    = Wp;
    P.x1b   = x1b;
    P.h8    = h8;
    P.rsc   = rsc;
    P.b1    = (const float*)d_in[5];
    P.g1    = (const float*)d_in[8];
    P.be1   = (const float*)d_in[9];
    P.b2    = (const float*)d_in[7];
    P.g2    = (const float*)d_in[10];
    P.be2   = (const float*)d_in[11];
    P.out   = (float*)d_out;
    P.bar   = bar;

    (void)hipMemsetAsync(bar, 0, 256, stream);       // barrier counter = 0
    fused_gcn<<<NBLK, 256, 0, stream>>>(P);
}

// Round 6
// 639.541 us; speedup vs baseline: 1.0967x; 1.0967x over previous
//
#include <hip/hip_runtime.h>

#define N_NODES 50000
#define N_EDGES 600000
#define DIM     128
#define VOCAB   512
#define LN_EPS  1e-5f
#define FIX20   1048576.0f    // 2^20 fixed-point scale for weight sums (26-bit field)
#define WSC     65535.0f      // 16-bit fixed-point scale for edge weights
#define BCAP    64            // fixed CSR bucket capacity (max in-degree << 64)
#define NBLK    1024          // 4 blocks/CU x 256 CUs -> all co-resident

typedef unsigned int uint;
typedef unsigned long long ull;
typedef unsigned short ushort;
typedef __attribute__((ext_vector_type(8))) short s8v;   // 8 bf16 (4 VGPRs)
typedef __attribute__((ext_vector_type(4))) float f4v;   // 4 fp32 acc
typedef __attribute__((ext_vector_type(4))) int   i4v;
typedef __attribute__((ext_vector_type(4))) float fv4;
typedef __attribute__((ext_vector_type(2))) float f2v;

// round-to-nearest-even fp32 -> bf16 (as uint16 in low bits)
__device__ __forceinline__ uint f2bf(float f) {
    uint u = __float_as_uint(f);
    return (u + 0x7fffu + ((u >> 16) & 1u)) >> 16;
}
__device__ __forceinline__ float bf_lo(uint p) { return __uint_as_float(p << 16); }
__device__ __forceinline__ float bf_hi(uint p) { return __uint_as_float(p & 0xffff0000u); }
// pack word: {count:6 | fixsum:26}, fixsum scaled by 2^20
__device__ __forceinline__ float dis_of(uint pv) {
    return rsqrtf(1.0f + (float)(pv & 0x03ffffffu) * (1.0f / FIX20));
}

// Manual grid barrier (persistent kernel; all NBLK blocks co-resident by
// __launch_bounds__(256,4) + grid = 4*CUs). Monotonic counter.
// CRITICAL (round-5 lesson): poll RELAXED — an agent-scope ACQUIRE poll
// invalidates the XCD's L2 every iteration, thrashing every working block's
// cache (5x slowdown). One acquire fence AFTER the count is reached imports
// all releases at a single point.
__device__ __forceinline__ void grid_bar(uint* cnt, uint target) {
    __syncthreads();                                  // block's stores drained
    if (threadIdx.x == 0) {
        __hip_atomic_fetch_add(cnt, 1u, __ATOMIC_RELEASE, __HIP_MEMORY_SCOPE_AGENT);
        while (__hip_atomic_load(cnt, __ATOMIC_RELAXED, __HIP_MEMORY_SCOPE_AGENT)
               < target)
            __builtin_amdgcn_s_sleep(8);
        __builtin_amdgcn_fence(__ATOMIC_ACQUIRE, "agent");   // one L2 inv total
    }
    __syncthreads();
}

struct GcnParams {
    const int*   ei;     // [2,E]
    const float* ew;
    uint2*       pairN;  // {pack: count|fixsum, nid}
    const int*   nid;
    uint*        epack;  // buckets: {src:16|w16}
    const float* emb;
    const float* W1;
    uint*        hembB;  // emb@W1 bf16x2
    const float* W2;
    ushort*      Wp;     // W2 MFMA B-frags
    uint*        x1b;    // layer-1 out bf16x2
    char*        h8;     // layer-2 matmul int8
    float*       rsc;    // per-row scale (carries dis)
    const float* b1; const float* g1; const float* be1;
    const float* b2; const float* g2; const float* be2;
    float*       out;
    uint*        bar;    // grid barrier counter
};

// ---------------------------------------------------------------------------
// Phase-1 sub-path: per-edge 32-bit atomic {count:6, fixsum:26} -> rank,
// then direct 4B-record scatter epack[dst*BCAP + rank] = {src:16 | w16}.
__device__ __forceinline__ void deg_step(int vb, int tid, const GcnParams& P) {
    int e0 = (vb * 256 + tid) * 4;
    if (e0 >= N_EDGES) return;
    i4v s4 = __builtin_nontemporal_load((const i4v*)(P.ei + e0));
    i4v c4 = __builtin_nontemporal_load((const i4v*)(P.ei + N_EDGES + e0));
    fv4 w4 = __builtin_nontemporal_load((const fv4*)(P.ew + e0));
    int   s[4] = {s4.x, s4.y, s4.z, s4.w};
    int   c[4] = {c4.x, c4.y, c4.z, c4.w};
    float w[4] = {w4.x, w4.y, w4.z, w4.w};
    uint r[4];
    #pragma unroll
    for (int k = 0; k < 4; k++) {
        uint a = (1u << 26) | (uint)__float2int_rn(w[k] * FIX20);
        r[k] = atomicAdd(&((uint*)P.pairN)[2 * (size_t)c[k]], a);
    }
    #pragma unroll
    for (int k = 0; k < 4; k++) {
        uint rk = r[k] >> 26;                        // rank among dst's edges
        uint wq = (uint)__float2int_rn(w[k] * WSC);
        P.epack[(size_t)c[k] * BCAP + rk] = (uint)s[k] | (wq << 16);
    }
}

// Phase-1 sub-path: layer-1 matmul Hb = emb @ W1 (fp32 -> bf16x2), 64 rows/vb.
__device__ __forceinline__ void mm1_step(int bx, int tid, float* Wt, float* Xt,
                                         const GcnParams& P) {
    const float* X = P.emb;
    const float* W = P.W1;
    int tx = tid & 31, ty = tid >> 5;
    int r0 = bx * 64;
    float acc[8][4];
    #pragma unroll
    for (int j = 0; j < 8; j++)
        #pragma unroll
        for (int c = 0; c < 4; c++) acc[j][c] = 0.f;

    for (int kb = 0; kb < 128; kb += 32) {
        __syncthreads();
        #pragma unroll
        for (int q = 0; q < 4; q++) {
            int f = q * 256 + tid;
            ((float4*)Wt)[f] = *(const float4*)(W + kb * 128 + f * 4);
        }
        #pragma unroll
        for (int q = 0; q < 2; q++) {
            int f = q * 256 + tid;
            int row = f >> 3, cs = f & 7;
            int gr = r0 + row;
            float4 xv = make_float4(0.f, 0.f, 0.f, 0.f);
            if (gr < VOCAB) xv = *(const float4*)(X + (size_t)gr * 128 + kb + cs * 4);
            *(float4*)(Xt + row * 36 + cs * 4) = xv;
        }
        __syncthreads();
        #pragma unroll
        for (int k = 0; k < 32; k += 4) {
            float wv[4][4];
            #pragma unroll
            for (int kk = 0; kk < 4; kk++) {
                float4 t4 = *(const float4*)(Wt + (k + kk) * 128 + tx * 4);
                wv[kk][0] = t4.x; wv[kk][1] = t4.y; wv[kk][2] = t4.z; wv[kk][3] = t4.w;
            }
            #pragma unroll
            for (int j = 0; j < 8; j++) {
                float4 xv = *(const float4*)(Xt + (ty * 8 + j) * 36 + k);
                float xs[4] = {xv.x, xv.y, xv.z, xv.w};
                #pragma unroll
                for (int kk = 0; kk < 4; kk++)
                    #pragma unroll
                    for (int c = 0; c < 4; c++)
                        acc[j][c] = fmaf(xs[kk], wv[kk][c], acc[j][c]);
            }
        }
    }
    #pragma unroll
    for (int j = 0; j < 8; j++) {
        int gr = r0 + ty * 8 + j;
        if (gr < VOCAB) {
            uint p0 = f2bf(acc[j][0]) | (f2bf(acc[j][1]) << 16);
            uint p1 = f2bf(acc[j][2]) | (f2bf(acc[j][3]) << 16);
            ((uint2*)P.hembB)[(size_t)gr * 32 + tx] = make_uint2(p0, p1);
        }
    }
}

// Phase-1 sub-path: W2 prepack (16384 elems) then pairN[i].y = node_ids[i]
// (nid words disjoint from the atomic pack words -> no ordering hazard).
__device__ __forceinline__ void prep_step(int o, const GcnParams& P) {
    if (o < 16384) {
        int j = o & 7, lane = (o >> 3) & 63, chunk = o >> 9;
        int kc = chunk & 3, nc = chunk >> 2;
        int k = kc * 32 + (lane >> 4) * 8 + j;
        int n = nc * 16 + (lane & 15);
        P.Wp[o] = (ushort)f2bf(P.W2[k * 128 + n]);
    } else {
        int i = o - 16384;
        if (i < N_NODES) ((uint*)P.pairN)[2 * (size_t)i + 1] = (uint)P.nid[i];
    }
}

// ---------------------------------------------------------------------------
// Phase 3: MFMA bf16 matmul (layer 2), per-row int8 output.
// rowscale[r] = max|row r|/127 * dis[r]  (dis folded -> agg2 uses raw w).
__device__ __forceinline__ void mm2_step(int wid, int lane, const GcnParams& P) {
    int r0 = wid * 16;
    if (r0 >= N_NODES) return;
    int quad = lane >> 4, lo = lane & 15;
    const uint* xrow = P.x1b + (size_t)(r0 + lo) * 64 + quad * 4;
    s8v a[4];
    #pragma unroll
    for (int kc = 0; kc < 4; kc++) a[kc] = *(const s8v*)(xrow + kc * 16);
    f4v acc[8];
    #pragma unroll
    for (int nc = 0; nc < 8; nc++) {
        acc[nc] = (f4v){0.f, 0.f, 0.f, 0.f};
        #pragma unroll
        for (int kc = 0; kc < 4; kc++) {
            s8v b = *(const s8v*)(P.Wp + (size_t)((nc * 4 + kc) * 64 + lane) * 8);
            acc[nc] = __builtin_amdgcn_mfma_f32_16x16x32_bf16(a[kc], b, acc[nc], 0, 0, 0);
        }
    }
    float m[4];
    #pragma unroll
    for (int r = 0; r < 4; r++) {
        m[r] = 0.f;
        #pragma unroll
        for (int nc = 0; nc < 8; nc++) m[r] = fmaxf(m[r], fabsf(acc[nc][r]));
    }
    #pragma unroll
    for (int o = 1; o <= 8; o <<= 1)
        #pragma unroll
        for (int r = 0; r < 4; r++) m[r] = fmaxf(m[r], __shfl_xor(m[r], o, 64));
    #pragma unroll
    for (int r = 0; r < 4; r++) {
        float inv = (m[r] > 0.f) ? 127.0f / m[r] : 0.f;
        if (lo == 0) {
            int rr = r0 + quad * 4 + r;
            P.rsc[rr] = m[r] * (1.0f / 127.0f) * dis_of(P.pairN[rr].x);
        }
        char* hp = P.h8 + (size_t)(r0 + quad * 4 + r) * 128 + lo;
        #pragma unroll
        for (int nc = 0; nc < 8; nc++)
            hp[nc * 16] = (char)__float2int_rn(acc[nc][r] * inv);
    }
}

// ---------------------------------------------------------------------------
// Phases 2/4: fused aggregation + self-loop + bias + residual + LN.
// One wave per node; lane owns dims {2*lane, 2*lane+1}.
// Batch-16 MLP: 16 records in 4 uniform uint4 loads, then ALL level-2
// gathers, then ALL row gathers -> ~3 serial round trips per node.
template<bool RESID_BF, bool OUT_BF, bool GI8>
__device__ __forceinline__ void agg_step(int i, int lane,
        const uint2* __restrict__ pairN, const uint* __restrict__ epack,
        const void* __restrict__ hb, const float* __restrict__ rowscale,
        const void* __restrict__ resid, const float* __restrict__ bias,
        const float* __restrict__ gamma, const float* __restrict__ beta,
        void* __restrict__ out) {
    int iw = __builtin_amdgcn_readfirstlane(i);      // wave-uniform
    uint2 pnw = pairN[iw];
    uint pv = pnw.x;
    int deg = (int)(pv >> 26);
    float dl = dis_of(pv);
    int hri = GI8 ? iw : (int)pnw.y;
    float slo, shi;
    if (GI8) {
        uint ps = ((const ushort*)hb)[(size_t)hri * 64 + lane];
        float sc0 = rowscale[hri];                   // folded: dl * raw_scale
        slo = sc0 * (float)(signed char)(ps & 0xffu);
        shi = sc0 * (float)(signed char)(ps >> 8);
    } else {
        uint ps = ((const uint*)hb)[(size_t)hri * 64 + lane];
        slo = bf_lo(ps); shi = bf_hi(ps);
    }
    // self-loop: final *dl gives dl^2*h (GI8: sc already carries one dl)
    float sx[4] = {GI8 ? slo : dl * slo, 0.f, 0.f, 0.f};
    float sy[4] = {GI8 ? shi : dl * shi, 0.f, 0.f, 0.f};
    const uint* ep = epack + (size_t)iw * BCAP;

    for (int j0 = 0; j0 < deg; j0 += 16) {
        uint4 rv0 = ((const uint4*)(ep + j0))[0];
        uint4 rv1 = ((const uint4*)(ep + j0))[1];
        uint4 rv2 = ((const uint4*)(ep + j0))[2];
        uint4 rv3 = ((const uint4*)(ep + j0))[3];
        uint rec[16] = {rv0.x, rv0.y, rv0.z, rv0.w,
                        rv1.x, rv1.y, rv1.z, rv1.w,
                        rv2.x, rv2.y, rv2.z, rv2.w,
                        rv3.x, rv3.y, rv3.z, rv3.w};
        uint src[16];
        #pragma unroll
        for (int k = 0; k < 16; k++)
            src[k] = (j0 + k < deg) ? (rec[k] & 0xffffu) : 0u;   // clamp -> safe row
        uint qv[16];
        float scv[16];
        if (GI8) {
            #pragma unroll
            for (int k = 0; k < 16; k++)
                qv[k] = ((const ushort*)hb)[(size_t)src[k] * 64 + lane];
            #pragma unroll
            for (int k = 0; k < 16; k++)
                scv[k] = rowscale[src[k]];
        } else {
            uint2 pnk[16];
            #pragma unroll
            for (int k = 0; k < 16; k++)
                pnk[k] = pairN[src[k]];              // {pack, nid} one gather
            #pragma unroll
            for (int k = 0; k < 16; k++)
                qv[k] = ((const uint*)hb)[(size_t)pnk[k].y * 64 + lane];
            #pragma unroll
            for (int k = 0; k < 16; k++)
                scv[k] = (float)(pnk[k].x & 0x03ffffffu);
        }
        #pragma unroll
        for (int k = 0; k < 16; k++) {
            float w = (j0 + k < deg) ? (float)(rec[k] >> 16) * (1.0f / WSC) : 0.f;
            float lo, hi;
            if (GI8) {
                w *= scv[k];                         // raw w * (dis_src*scale_src)
                lo = (float)(signed char)(qv[k] & 0xffu);
                hi = (float)(signed char)(qv[k] >> 8);
            } else {
                w *= rsqrtf(1.0f + scv[k] * (1.0f / FIX20));
                lo = bf_lo(qv[k]); hi = bf_hi(qv[k]);
            }
            sx[k & 3] += w * lo;
            sy[k & 3] += w * hi;
        }
    }
    float acc0 = (sx[0] + sx[1]) + (sx[2] + sx[3]);
    float acc1 = (sy[0] + sy[1]) + (sy[2] + sy[3]);
    float2 xr;
    if (RESID_BF) {
        uint pr = __builtin_nontemporal_load((const uint*)resid + (size_t)hri * 64 + lane);
        xr = make_float2(bf_lo(pr), bf_hi(pr));
    } else {
        xr = ((const float2*)resid)[(size_t)hri * 64 + lane];
    }
    float2 bi = ((const float2*)bias)[lane];
    float v0 = xr.x + dl * acc0 + bi.x;
    float v1 = xr.y + dl * acc1 + bi.y;
    float s1 = v0 + v1, s2 = v0 * v0 + v1 * v1;
    #pragma unroll
    for (int o = 32; o > 0; o >>= 1) {
        s1 += __shfl_xor(s1, o, 64);
        s2 += __shfl_xor(s2, o, 64);
    }
    float mu   = s1 * (1.0f / DIM);
    float var  = s2 * (1.0f / DIM) - mu * mu;
    float rstd = rsqrtf(var + LN_EPS);
    float2 ga = ((const float2*)gamma)[lane];
    float2 be = ((const float2*)beta)[lane];
    float o0 = (v0 - mu) * rstd * ga.x + be.x;
    float o1 = (v1 - mu) * rstd * ga.y + be.y;
    if (OUT_BF) {
        __builtin_nontemporal_store(f2bf(o0) | (f2bf(o1) << 16),
                                    (uint*)out + (size_t)i * 64 + lane);
    } else {
        f2v ov = {o0, o1};
        __builtin_nontemporal_store(ov, (f2v*)((float2*)out + (size_t)i * 64 + lane));
    }
}

// ---------------------------------------------------------------------------
// ONE persistent kernel, plain launch. 1024 blocks x 256 threads;
// __launch_bounds__(256,4) caps VGPR at 128 (current use 84) and LDS
// 25.6KB x 4 = 102KB <= 160KB -> 4 blocks/CU co-resident guaranteed,
// so the manual grid barrier cannot deadlock.
__global__ __launch_bounds__(256, 4) void fused_gcn(GcnParams P) {
    __shared__ float Wt[32 * 128];
    __shared__ float Xt[64 * 36];
    int tid = threadIdx.x;
    int bid = blockIdx.x;
    const int nb = NBLK;
    int lane = tid & 63, wv = tid >> 6;

    // ---- phase 0: zero pairN (replaces hipMemsetAsync) ----
    for (int t = bid * 256 + tid; t < N_NODES * 2; t += nb * 256)
        ((uint*)P.pairN)[t] = 0u;
    grid_bar(P.bar, 1 * nb);

    // ---- phase 1: deg atomics + scatter | mm1 | W2/nid prep ----
    constexpr int nbDeg = (N_EDGES / 4 + 255) / 256;       // 586
    constexpr int nmm   = (VOCAB + 63) / 64;               // 8
    constexpr int nTail = 64 + (N_NODES + 255) / 256;      // 260
    constexpr int NVB1  = nbDeg + nmm + nTail;             // 854
    for (int vb = bid; vb < NVB1; vb += nb) {
        if (vb < nbDeg)            deg_step(vb, tid, P);
        else if (vb < nbDeg + nmm) mm1_step(vb - nbDeg, tid, Wt, Xt, P);
        else                       prep_step((vb - nbDeg - nmm) * 256 + tid, P);
    }
    grid_bar(P.bar, 2 * nb);

    // ---- phase 2: agg1 (bf16 vocab table; {dis,nid}[src] via pairN) ----
    constexpr int NVBA = (N_NODES + 3) / 4;                // 12500
    for (int vb = bid; vb < NVBA; vb += nb) {
        int i = vb * 4 + wv;
        if (i < N_NODES)
            agg_step<false, true, false>(i, lane, P.pairN, P.epack, P.hembB,
                                         nullptr, P.emb, P.b1, P.g1, P.be1, P.x1b);
    }
    grid_bar(P.bar, 3 * nb);

    // ---- phase 3: mm2 (MFMA -> int8, rowscale folds dis) ----
    constexpr int NVB3 = (N_NODES / 16 + 3) / 4;           // 782
    for (int vb = bid; vb < NVB3; vb += nb)
        mm2_step(vb * 4 + wv, lane, P);
    grid_bar(P.bar, 4 * nb);

    // ---- phase 4: agg2 (int8 table, rowscale-folded weights) -> out ----
    for (int vb = bid; vb < NVBA; vb += nb) {
        int i = vb * 4 + wv;
        if (i < N_NODES)
            agg_step<true, false, true>(i, lane, P.pairN, P.epack, P.h8,
                                        P.rsc, P.x1b, P.b2, P.g2, P.be2, P.out);
    }
}

// ---------------------------------------------------------------------------
extern "C" void kernel_launch(void* const* d_in, const int* in_sizes, int n_in,
                              void* d_out, int out_size, void* d_ws, size_t ws_size,
                              hipStream_t stream) {
    // workspace carve-out (256B aligned)
    char* p = (char*)d_ws;
    auto alloc = [&](size_t bytes) {
        char* r = p;
        p += (bytes + 255) & ~(size_t)255;
        return r;
    };
    char*   h8      = (char*)  alloc((size_t)N_NODES * DIM);       // 6.4 MB int8
    float*  rsc     = (float*) alloc((size_t)N_NODES * 4);         // 200 KB scales
    uint*   x1b     = (uint*)  alloc((size_t)N_NODES * 64 * 4);    // 12.8 MB bf16x2
    uint*   hembB   = (uint*)  alloc((size_t)VOCAB * 64 * 4);      // 128 KB bf16x2
    ushort* Wp      = (ushort*)alloc((size_t)128 * 128 * 2);       // 32 KB B-frags
    uint2*  pairN   = (uint2*) alloc((size_t)N_NODES * 8);         // 400 KB {pack,nid}
    uint*   epack   = (uint*)  alloc((size_t)N_NODES * BCAP * 4);  // 12.8 MB
    uint*   bar     = (uint*)  alloc(256);                         // grid barrier

    GcnParams P;
    P.ei    = (const int*)  d_in[1];
    P.ew    = (const float*)d_in[2];
    P.pairN = pairN;
    P.nid   = (const int*)  d_in[0];
    P.epack = epack;
    P.emb   = (const float*)d_in[3];
    P.W1    = (const float*)d_in[4];
    P.hembB = hembB;
    P.W2    = (const float*)d_in[6];
    P.Wp    = Wp;
    P.x1b   = x1b;
    P.h8    = h8;
    P.rsc   = rsc;
    P.b1    = (const float*)d_in[5];
    P.g1    = (const float*)d_in[8];
    P.be1   = (const float*)d_in[9];
    P.b2    = (const float*)d_in[7];
    P.g2    = (const float*)d_in[10];
    P.be2   = (const float*)d_in[11];
    P.out   = (float*)d_out;
    P.bar   = bar;

    (void)hipMemsetAsync(bar, 0, 256, stream);       // barrier counter = 0
    fused_gcn<<<NBLK, 256, 0, stream>>>(P);
}

// Round 10
// 207.708 us; speedup vs baseline: 3.3767x; 3.0790x over previous
//
#include <hip/hip_runtime.h>

#define N_NODES 50000
#define N_EDGES 600000
#define DIM     128
#define VOCAB   512
#define LN_EPS  1e-5f
#define FIX20   1048576.0f    // 2^20 fixed-point scale for weight sums (26-bit field)
#define WSC     65535.0f      // 16-bit fixed-point scale for edge weights
#define BCAP    64            // fixed CSR bucket capacity (max in-degree << 64)

typedef unsigned int uint;
typedef unsigned long long ull;
typedef unsigned short ushort;
typedef __attribute__((ext_vector_type(8))) short s8v;   // 8 bf16 (4 VGPRs)
typedef __attribute__((ext_vector_type(4))) float f4v;   // 4 fp32 acc
typedef __attribute__((ext_vector_type(4))) int   i4v;
typedef __attribute__((ext_vector_type(4))) float fv4;
typedef __attribute__((ext_vector_type(2))) float f2v;

// round-to-nearest-even fp32 -> bf16 (as uint16 in low bits)
__device__ __forceinline__ uint f2bf(float f) {
    uint u = __float_as_uint(f);
    return (u + 0x7fffu + ((u >> 16) & 1u)) >> 16;
}
__device__ __forceinline__ float bf_lo(uint p) { return __uint_as_float(p << 16); }
__device__ __forceinline__ float bf_hi(uint p) { return __uint_as_float(p & 0xffff0000u); }
// pack word: {count:6 | fixsum:26}, fixsum scaled by 2^20
__device__ __forceinline__ float dis_of(uint pv) {
    return rsqrtf(1.0f + (float)(pv & 0x03ffffffu) * (1.0f / FIX20));
}

// ---------------------------------------------------------------------------
// K1 (fused): blocks [0, nbDeg): per-edge 32-bit atomic {count:6, fixsum:26}
//   on pairN[dst].x -> rank, then DIRECT scatter of a 4-byte record
//   epack[dst*BCAP + rank] = {src:16 | w_fixed16:16}.
// blocks [nbDeg, nbDeg+nmm): layer-1 matmul Hb = emb @ W1 (fp32 -> bf16x2).
// remaining blocks: W2 prepack (16384 elems) then pairN[i].y = node_ids[i]
//   (nid words disjoint from the atomic pack words -> no ordering hazard).
__global__ __launch_bounds__(256) void deg_mm1_kernel(
        const int* __restrict__ ei, const float* __restrict__ ew,
        uint2* pairN, const int* __restrict__ nid, uint* __restrict__ epack, int E,
        const float* __restrict__ X, const float* __restrict__ W,
        uint* __restrict__ Hb, int M,
        const float* __restrict__ W2, ushort* __restrict__ Wp) {
    __shared__ float Wt[32 * 128];
    __shared__ float Xt[64 * 36];
    int tid = threadIdx.x;
    int nbDeg = (E / 4 + 255) / 256;
    int nmm = (M + 63) / 64;
    if ((int)blockIdx.x < nbDeg) {
        // ---- deg/rank + direct bucket scatter: 4 independent chains ----
        int e0 = (blockIdx.x * 256 + tid) * 4;
        if (e0 >= E) return;
        i4v s4 = __builtin_nontemporal_load((const i4v*)(ei + e0));
        i4v c4 = __builtin_nontemporal_load((const i4v*)(ei + E + e0));
        fv4 w4 = __builtin_nontemporal_load((const fv4*)(ew + e0));
        int   s[4] = {s4.x, s4.y, s4.z, s4.w};
        int   c[4] = {c4.x, c4.y, c4.z, c4.w};
        float w[4] = {w4.x, w4.y, w4.z, w4.w};
        uint r[4];
        #pragma unroll
        for (int k = 0; k < 4; k++) {
            uint a = (1u << 26) | (uint)__float2int_rn(w[k] * FIX20);
            r[k] = atomicAdd(&((uint*)pairN)[2 * (size_t)c[k]], a);
        }
        #pragma unroll
        for (int k = 0; k < 4; k++) {
            uint rk = r[k] >> 26;                        // rank among dst's edges
            uint wq = (uint)__float2int_rn(w[k] * WSC);
            epack[(size_t)c[k] * BCAP + rk] = (uint)s[k] | (wq << 16);
        }
        return;
    }
    if ((int)blockIdx.x >= nbDeg + nmm) {
        int o = (blockIdx.x - nbDeg - nmm) * 256 + tid;
        if (o < 16384) {
            // ---- W2 prepack path ----
            int j = o & 7, lane = (o >> 3) & 63, chunk = o >> 9;
            int kc = chunk & 3, nc = chunk >> 2;
            int k = kc * 32 + (lane >> 4) * 8 + j;
            int n = nc * 16 + (lane & 15);
            Wp[o] = (ushort)f2bf(W2[k * 128 + n]);
        } else {
            // ---- pairN nid-fill path ----
            int i = o - 16384;
            if (i < N_NODES) ((uint*)pairN)[2 * (size_t)i + 1] = (uint)nid[i];
        }
        return;
    }
    // ---- layer-1 matmul path ----
    int bx = blockIdx.x - nbDeg;
    int tx = tid & 31, ty = tid >> 5;
    int r0 = bx * 64;
    float acc[8][4];
    #pragma unroll
    for (int j = 0; j < 8; j++)
        #pragma unroll
        for (int c = 0; c < 4; c++) acc[j][c] = 0.f;

    for (int kb = 0; kb < 128; kb += 32) {
        __syncthreads();
        #pragma unroll
        for (int q = 0; q < 4; q++) {
            int f = q * 256 + tid;
            ((float4*)Wt)[f] = *(const float4*)(W + kb * 128 + f * 4);
        }
        #pragma unroll
        for (int q = 0; q < 2; q++) {
            int f = q * 256 + tid;
            int row = f >> 3, cs = f & 7;
            int gr = r0 + row;
            float4 xv = make_float4(0.f, 0.f, 0.f, 0.f);
            if (gr < M) xv = *(const float4*)(X + (size_t)gr * 128 + kb + cs * 4);
            *(float4*)(Xt + row * 36 + cs * 4) = xv;
        }
        __syncthreads();
        #pragma unroll
        for (int k = 0; k < 32; k += 4) {
            float wv[4][4];
            #pragma unroll
            for (int kk = 0; kk < 4; kk++) {
                float4 t4 = *(const float4*)(Wt + (k + kk) * 128 + tx * 4);
                wv[kk][0] = t4.x; wv[kk][1] = t4.y; wv[kk][2] = t4.z; wv[kk][3] = t4.w;
            }
            #pragma unroll
            for (int j = 0; j < 8; j++) {
                float4 xv = *(const float4*)(Xt + (ty * 8 + j) * 36 + k);
                float xs[4] = {xv.x, xv.y, xv.z, xv.w};
                #pragma unroll
                for (int kk = 0; kk < 4; kk++)
                    #pragma unroll
                    for (int c = 0; c < 4; c++)
                        acc[j][c] = fmaf(xs[kk], wv[kk][c], acc[j][c]);
            }
        }
    }
    #pragma unroll
    for (int j = 0; j < 8; j++) {
        int gr = r0 + ty * 8 + j;
        if (gr < M) {
            uint p0 = f2bf(acc[j][0]) | (f2bf(acc[j][1]) << 16);
            uint p1 = f2bf(acc[j][2]) | (f2bf(acc[j][3]) << 16);
            ((uint2*)Hb)[(size_t)gr * 32 + tx] = make_uint2(p0, p1);
        }
    }
}

// ---------------------------------------------------------------------------
// agg1 core: aggregation + self-loop + bias + residual(emb row) + LN for ONE
// node; returns packed bf16x2 {dim 2*lane, 2*lane+1}. Batch-16 MLP (1 record
// round-trip, then all pairN gathers, then all row gathers).
__device__ __forceinline__ uint agg1_node(int i, int lane,
        const uint2* __restrict__ pairN, const uint* __restrict__ epack,
        const uint* __restrict__ hb, const float* __restrict__ emb,
        const float* __restrict__ bias, const float* __restrict__ gamma,
        const float* __restrict__ beta, uint* __restrict__ x1b) {
    int iw = __builtin_amdgcn_readfirstlane(i);      // wave-uniform
    uint2 pnw = pairN[iw];
    uint pv = pnw.x;
    int deg = (int)(pv >> 26);
    float dl = dis_of(pv);
    int hri = (int)pnw.y;                            // vocab row of node i
    uint ps = hb[(size_t)hri * 64 + lane];
    float slo = bf_lo(ps), shi = bf_hi(ps);
    float sx[4] = {dl * slo, 0.f, 0.f, 0.f};         // self-loop (dl^2 after *dl)
    float sy[4] = {dl * shi, 0.f, 0.f, 0.f};
    const uint* ep = epack + (size_t)iw * BCAP;

    for (int j0 = 0; j0 < deg; j0 += 16) {
        uint4 rv0 = ((const uint4*)(ep + j0))[0];
        uint4 rv1 = ((const uint4*)(ep + j0))[1];
        uint4 rv2 = ((const uint4*)(ep + j0))[2];
        uint4 rv3 = ((const uint4*)(ep + j0))[3];
        uint rec[16] = {rv0.x, rv0.y, rv0.z, rv0.w,
                        rv1.x, rv1.y, rv1.z, rv1.w,
                        rv2.x, rv2.y, rv2.z, rv2.w,
                        rv3.x, rv3.y, rv3.z, rv3.w};
        uint src[16];
        #pragma unroll
        for (int k = 0; k < 16; k++)
            src[k] = (j0 + k < deg) ? (rec[k] & 0xffffu) : 0u;   // clamp -> safe row
        uint2 pnk[16];
        #pragma unroll
        for (int k = 0; k < 16; k++)
            pnk[k] = pairN[src[k]];                  // {pack, nid} one gather
        uint qv[16];
        #pragma unroll
        for (int k = 0; k < 16; k++)
            qv[k] = hb[(size_t)pnk[k].y * 64 + lane];
        #pragma unroll
        for (int k = 0; k < 16; k++) {
            float w = (j0 + k < deg) ? (float)(rec[k] >> 16) * (1.0f / WSC) : 0.f;
            w *= rsqrtf(1.0f + (float)(pnk[k].x & 0x03ffffffu) * (1.0f / FIX20));
            sx[k & 3] += w * bf_lo(qv[k]);
            sy[k & 3] += w * bf_hi(qv[k]);
        }
    }
    float acc0 = (sx[0] + sx[1]) + (sx[2] + sx[3]);
    float acc1 = (sy[0] + sy[1]) + (sy[2] + sy[3]);
    float2 xr = ((const float2*)emb)[(size_t)hri * 64 + lane];   // fp32 residual
    float2 bi = ((const float2*)bias)[lane];
    float v0 = xr.x + dl * acc0 + bi.x;
    float v1 = xr.y + dl * acc1 + bi.y;
    float s1 = v0 + v1, s2 = v0 * v0 + v1 * v1;
    #pragma unroll
    for (int o = 32; o > 0; o >>= 1) {
        s1 += __shfl_xor(s1, o, 64);
        s2 += __shfl_xor(s2, o, 64);
    }
    float mu   = s1 * (1.0f / DIM);
    float var  = s2 * (1.0f / DIM) - mu * mu;
    float rstd = rsqrtf(var + LN_EPS);
    float2 ga = ((const float2*)gamma)[lane];
    float2 be = ((const float2*)beta)[lane];
    float o0 = (v0 - mu) * rstd * ga.x + be.x;
    float o1 = (v1 - mu) * rstd * ga.y + be.y;
    uint pw = f2bf(o0) | (f2bf(o1) << 16);
    __builtin_nontemporal_store(pw, x1b + (size_t)i * 64 + lane);
    return pw;
}

// ---------------------------------------------------------------------------
// K2 (fused agg1 + mm2): one block = 16 consecutive nodes. 4 waves x 4 serial
// nodes each produce the LN output (bf16x2) -> LDS tile Xs[16][68] (+4 pad
// breaks the 256B-stride bank conflict) + global x1b (residual for agg2).
// Then the SAME block runs the 16-row MFMA tile of layer-2 (h2 = x1 @ W2):
// each wave does 2 of 8 column-chunks; cross-wave row-max via LDS; per-row
// int8 quantization; rowscale[r] = max/127 * dis[r] (dis folded for agg2).
// Removes the separate mm2 dispatch and its 12.8 MB x1b re-read.
__global__ __launch_bounds__(256) void agg1_mm2(
        const uint2* __restrict__ pairN, const uint* __restrict__ epack,
        const uint* __restrict__ hembB, const ushort* __restrict__ Wp,
        const float* __restrict__ emb,
        const float* __restrict__ b1, const float* __restrict__ g1,
        const float* __restrict__ be1,
        uint* __restrict__ x1b, char* __restrict__ h8,
        float* __restrict__ rsc) {
    __shared__ uint  Xs[16][68];                     // 16 rows x 64 (+4 pad)
    __shared__ float wmax[4][4][4];                  // [wave][quad][r]
    int tid = threadIdx.x, lane = tid & 63, wv = tid >> 6;
    int b0 = blockIdx.x * 16;                        // 3125 * 16 = 50000 exactly

    // ---- phase A: aggregation+LN for this block's 16 nodes ----
    #pragma unroll
    for (int t = 0; t < 4; t++) {
        int row = wv * 4 + t;
        uint pw = agg1_node(b0 + row, lane, pairN, epack, hembB, emb,
                            b1, g1, be1, x1b);
        Xs[row][lane] = pw;
    }
    __syncthreads();

    // ---- phase B: 16-row MFMA tile, wave wv owns nc = 2wv, 2wv+1 ----
    int quad = lane >> 4, lo = lane & 15;
    s8v a[4];
    #pragma unroll
    for (int kc = 0; kc < 4; kc++)
        a[kc] = *(const s8v*)&Xs[lo][quad * 4 + kc * 16];
    f4v acc[2];
    #pragma unroll
    for (int c = 0; c < 2; c++) {
        int nc = wv * 2 + c;
        acc[c] = (f4v){0.f, 0.f, 0.f, 0.f};
        #pragma unroll
        for (int kc = 0; kc < 4; kc++) {
            s8v b = *(const s8v*)(Wp + (size_t)((nc * 4 + kc) * 64 + lane) * 8);
            acc[c] = __builtin_amdgcn_mfma_f32_16x16x32_bf16(a[kc], b, acc[c], 0, 0, 0);
        }
    }
    float m[4];
    #pragma unroll
    for (int r = 0; r < 4; r++)
        m[r] = fmaxf(fabsf(acc[0][r]), fabsf(acc[1][r]));
    #pragma unroll
    for (int o = 1; o <= 8; o <<= 1)
        #pragma unroll
        for (int r = 0; r < 4; r++) m[r] = fmaxf(m[r], __shfl_xor(m[r], o, 64));
    if (lo == 0)
        #pragma unroll
        for (int r = 0; r < 4; r++) wmax[wv][quad][r] = m[r];
    __syncthreads();
    float fm[4];
    #pragma unroll
    for (int r = 0; r < 4; r++)
        fm[r] = fmaxf(fmaxf(wmax[0][quad][r], wmax[1][quad][r]),
                      fmaxf(wmax[2][quad][r], wmax[3][quad][r]));
    #pragma unroll
    for (int r = 0; r < 4; r++) {
        float inv = (fm[r] > 0.f) ? 127.0f / fm[r] : 0.f;
        char* hp = h8 + (size_t)(b0 + quad * 4 + r) * 128 + lo;
        #pragma unroll
        for (int c = 0; c < 2; c++)
            hp[(wv * 2 + c) * 16] = (char)__float2int_rn(acc[c][r] * inv);
    }
    if (wv == 0 && lo == 0) {
        #pragma unroll
        for (int r = 0; r < 4; r++) {
            int rr = b0 + quad * 4 + r;
            rsc[rr] = fm[r] * (1.0f / 127.0f) * dis_of(pairN[rr].x);
        }
    }
}

// ---------------------------------------------------------------------------
// K3 (agg2): aggregation over int8 table + self-loop + bias + residual + LN.
// One wave per node; rowscale carries dis[src]*scale[src] -> raw w only.
__global__ __launch_bounds__(256) void agg2_ln(const uint2* __restrict__ pairN,
                                               const uint* __restrict__ epack,
                                               const ushort* __restrict__ hb,
                                               const float* __restrict__ rowscale,
                                               const uint* __restrict__ resid,
                                               const float* __restrict__ bias,
                                               const float* __restrict__ gamma,
                                               const float* __restrict__ beta,
                                               float* __restrict__ out, int n) {
    int i = (blockIdx.x * 256 + threadIdx.x) >> 6;
    int lane = threadIdx.x & 63;
    if (i >= n) return;
    int iw = __builtin_amdgcn_readfirstlane(i);      // wave-uniform
    uint pv = pairN[iw].x;
    int deg = (int)(pv >> 26);
    float dl = dis_of(pv);
    uint ps = hb[(size_t)iw * 64 + lane];
    float sc0 = rowscale[iw];                        // folded: dl * raw_scale
    float slo = sc0 * (float)(signed char)(ps & 0xffu);
    float shi = sc0 * (float)(signed char)(ps >> 8);
    float sx[4] = {slo, 0.f, 0.f, 0.f};              // sc0 already carries one dl
    float sy[4] = {shi, 0.f, 0.f, 0.f};
    const uint* ep = epack + (size_t)iw * BCAP;

    for (int j0 = 0; j0 < deg; j0 += 16) {
        uint4 rv0 = ((const uint4*)(ep + j0))[0];
        uint4 rv1 = ((const uint4*)(ep + j0))[1];
        uint4 rv2 = ((const uint4*)(ep + j0))[2];
        uint4 rv3 = ((const uint4*)(ep + j0))[3];
        uint rec[16] = {rv0.x, rv0.y, rv0.z, rv0.w,
                        rv1.x, rv1.y, rv1.z, rv1.w,
                        rv2.x, rv2.y, rv2.z, rv2.w,
                        rv3.x, rv3.y, rv3.z, rv3.w};
        uint src[16];
        #pragma unroll
        for (int k = 0; k < 16; k++)
            src[k] = (j0 + k < deg) ? (rec[k] & 0xffffu) : 0u;   // clamp -> safe row
        uint qv[16];
        float scv[16];
        #pragma unroll
        for (int k = 0; k < 16; k++)
            qv[k] = hb[(size_t)src[k] * 64 + lane];
        #pragma unroll
        for (int k = 0; k < 16; k++)
            scv[k] = rowscale[src[k]];
        #pragma unroll
        for (int k = 0; k < 16; k++) {
            float w = (j0 + k < deg) ? (float)(rec[k] >> 16) * (1.0f / WSC) : 0.f;
            w *= scv[k];                             // raw w * (dis_src*scale_src)
            sx[k & 3] += w * (float)(signed char)(qv[k] & 0xffu);
            sy[k & 3] += w * (float)(signed char)(qv[k] >> 8);
        }
    }
    float acc0 = (sx[0] + sx[1]) + (sx[2] + sx[3]);
    float acc1 = (sy[0] + sy[1]) + (sy[2] + sy[3]);
    uint pr = __builtin_nontemporal_load(resid + (size_t)iw * 64 + lane);
    float2 bi = ((const float2*)bias)[lane];
    float v0 = bf_lo(pr) + dl * acc0 + bi.x;
    float v1 = bf_hi(pr) + dl * acc1 + bi.y;
    float s1 = v0 + v1, s2 = v0 * v0 + v1 * v1;
    #pragma unroll
    for (int o = 32; o > 0; o >>= 1) {
        s1 += __shfl_xor(s1, o, 64);
        s2 += __shfl_xor(s2, o, 64);
    }
    float mu   = s1 * (1.0f / DIM);
    float var  = s2 * (1.0f / DIM) - mu * mu;
    float rstd = rsqrtf(var + LN_EPS);
    float2 ga = ((const float2*)gamma)[lane];
    float2 be = ((const float2*)beta)[lane];
    float o0 = (v0 - mu) * rstd * ga.x + be.x;
    float o1 = (v1 - mu) * rstd * ga.y + be.y;
    f2v ov = {o0, o1};
    __builtin_nontemporal_store(ov, (f2v*)((float2*)out + (size_t)i * 64 + lane));
}

// ---------------------------------------------------------------------------
extern "C" void kernel_launch(void* const* d_in, const int* in_sizes, int n_in,
                              void* d_out, int out_size, void* d_ws, size_t ws_size,
                              hipStream_t stream) {
    const int*   node_ids = (const int*)  d_in[0];
    const int*   ei       = (const int*)  d_in[1];   // [2, E]
    const float* ew       = (const float*)d_in[2];
    const float* emb      = (const float*)d_in[3];   // [VOCAB, 128]
    const float* W1       = (const float*)d_in[4];
    const float* b1       = (const float*)d_in[5];
    const float* W2       = (const float*)d_in[6];
    const float* b2       = (const float*)d_in[7];
    const float* g1       = (const float*)d_in[8];
    const float* be1      = (const float*)d_in[9];
    const float* g2       = (const float*)d_in[10];
    const float* be2      = (const float*)d_in[11];
    float* out = (float*)d_out;

    // workspace carve-out (256B aligned)
    char* p = (char*)d_ws;
    auto alloc = [&](size_t bytes) {
        char* r = p;
        p += (bytes + 255) & ~(size_t)255;
        return r;
    };
    char*   h8      = (char*)  alloc((size_t)N_NODES * DIM);       // 6.4 MB int8
    float*  rsc     = (float*) alloc((size_t)N_NODES * 4);         // 200 KB scales
    uint*   x1b     = (uint*)  alloc((size_t)N_NODES * 64 * 4);    // 12.8 MB bf16x2
    uint*   hembB   = (uint*)  alloc((size_t)VOCAB * 64 * 4);      // 128 KB bf16x2
    ushort* Wp      = (ushort*)alloc((size_t)128 * 128 * 2);       // 32 KB B-frags
    uint2*  pairN   = (uint2*) alloc((size_t)N_NODES * 8);         // 400 KB {pack,nid}
    uint*   epack   = (uint*)  alloc((size_t)N_NODES * BCAP * 4);  // 12.8 MB

    int nbDeg = (N_EDGES / 4 + 255) / 256;       // 586
    int nmm = (VOCAB + 63) / 64;                 // 8
    int nTail = 64 + (N_NODES + 255) / 256;      // W2 prepack + nid fill = 260

    // --- K1: deg atomics + 4B-record scatter + layer-1 matmul + W2/nid prep ---
    (void)hipMemsetAsync(pairN, 0, (size_t)N_NODES * 8, stream);
    deg_mm1_kernel<<<nbDeg + nmm + nTail, 256, 0, stream>>>(
        ei, ew, pairN, node_ids, epack, N_EDGES, emb, W1, hembB, VOCAB, W2, Wp);

    // --- K2: agg1+LN fused with mm2 (16 nodes/block, LDS tile, int8 out) ---
    agg1_mm2<<<N_NODES / 16, 256, 0, stream>>>(
        pairN, epack, hembB, Wp, emb, b1, g1, be1, x1b, h8, rsc);

    // --- K3: agg2 over int8 table (rowscale-folded weights) + LN -> out ---
    agg2_ln<<<(N_NODES + 3) / 4, 256, 0, stream>>>(
        pairN, epack, (const ushort*)h8, rsc, x1b, b2, g2, be2, out, N_NODES);
}